// Round 9
// baseline (946.645 us; speedup 1.0000x reference)
//
#include <hip/hip_runtime.h>

#define DEVINL static __device__ __forceinline__
// Single-wave workgroup: the wave's own lgkmcnt orders all its LDS ops; a
// compiler fence + lgkmcnt drain replaces __syncthreads entirely.
#define LDSBAR() asm volatile("s_waitcnt lgkmcnt(0)" ::: "memory")

typedef float v2f __attribute__((ext_vector_type(2)));

DEVINL v2f mk2(float a, float b) { v2f r; r.x = a; r.y = b; return r; }
// One V_PK_FMA_F32: two IEEE fp32 FMAs per lane per issue.
DEVINL v2f pkfma(v2f a, v2f b, v2f c) { return __builtin_elementwise_fma(a, b, c); }

DEVINL float tanh_fast(float x) {
  // tanh(x) = 1 - 2/(e^{2x}+1); e+1 in [1,inf] -> never NaN
  float e = __expf(2.0f * x);
  return 1.0f - 2.0f * __builtin_amdgcn_rcpf(e + 1.0f);
}

template <int CTRL>
DEVINL float dpp_add(float v) {
  int t = __builtin_amdgcn_update_dpp(0, __float_as_int(v), CTRL, 0xF, 0xF, true);
  return v + __int_as_float(t);
}
// Sum across each 32-lane half-wave; result replicated in all lanes of the half.
DEVINL float rsum32(float v) {
  v = dpp_add<0xB1>(v);    // quad_perm [1,0,3,2]  -> pair sums
  v = dpp_add<0x4E>(v);    // quad_perm [2,3,0,1]  -> quad sums
  v = dpp_add<0x141>(v);   // row_half_mirror      -> sums of 8
  v = dpp_add<0x140>(v);   // row_mirror           -> sums of 16
  v += __int_as_float(__builtin_amdgcn_ds_swizzle(__float_as_int(v), 0x401F)); // xor16
  return v;
}

// 32-wide dot vs an LDS row (uniform address within each half), packed fp32.
DEVINL float dot32(const float* hrow, const v2f* W, float bias) {
  const float4* hp = (const float4*)hrow;
  v2f a0 = mk2(bias, 0.f), a1 = mk2(0.f, 0.f);
  v2f a2 = mk2(0.f, 0.f), a3 = mk2(0.f, 0.f);
#pragma unroll
  for (int q = 0; q < 8; q += 2) {
    float4 x = hp[q], y = hp[q + 1];
    a0 = pkfma(mk2(x.x, x.y), W[2 * q + 0], a0);
    a1 = pkfma(mk2(x.z, x.w), W[2 * q + 1], a1);
    a2 = pkfma(mk2(y.x, y.y), W[2 * q + 2], a2);
    a3 = pkfma(mk2(y.z, y.w), W[2 * q + 3], a3);
  }
  v2f s = (a0 + a1) + (a2 + a3);
  return s.x + s.y;
}
// 16-wide partial dot (k-split r3 layer 1), packed fp32.
DEVINL float pdot16(const float* hrow, const v2f* W) {
  const float4* hp = (const float4*)hrow;
  v2f a0 = mk2(0.f, 0.f), a1 = mk2(0.f, 0.f);
  float4 x = hp[0], y = hp[1];
  a0 = pkfma(mk2(x.x, x.y), W[0], a0);
  a1 = pkfma(mk2(x.z, x.w), W[1], a1);
  a0 = pkfma(mk2(y.x, y.y), W[2], a0);
  a1 = pkfma(mk2(y.z, y.w), W[3], a1);
  x = hp[2]; y = hp[3];
  a0 = pkfma(mk2(x.x, x.y), W[4], a0);
  a1 = pkfma(mk2(x.z, x.w), W[5], a1);
  a0 = pkfma(mk2(y.x, y.y), W[6], a0);
  a1 = pkfma(mk2(y.z, y.w), W[7], a1);
  v2f s = a0 + a1;
  return s.x + s.y;
}

constexpr int TSTEPS = 256;

// wave = 1 batch element; lanes 0-31 = net r1 duties, lanes 32-63 = net r2.
// block = 64 (1 wave), grid = 4096. launch_bounds(64,4) -> 16 blocks/CU exact.
__global__ __launch_bounds__(64, 4) void reac_kernel(
    const float* __restrict__ useq,   // [B][T] f32
    const float* __restrict__ xz0,    // [B][26] f32
    const float* __restrict__ r1W0, const float* __restrict__ r1b0,
    const float* __restrict__ r1W1, const float* __restrict__ r1b1,
    const float* __restrict__ r1W2, const float* __restrict__ r1b2,
    const float* __restrict__ r2W0, const float* __restrict__ r2b0,
    const float* __restrict__ r2W1, const float* __restrict__ r2b1,
    const float* __restrict__ r2W2, const float* __restrict__ r2b2,
    const float* __restrict__ r3W0, const float* __restrict__ r3b0,
    const float* __restrict__ r3W1, const float* __restrict__ r3b1,
    const float* __restrict__ r3W2, const float* __restrict__ r3b2,
    float2* __restrict__ out)         // [B][T] -> (x0,x1) f32
{
  const int lane = threadIdx.x;
  const int j = lane & 31;
  const bool hi = lane >= 32;      // high half = r2 net
  const int b = blockIdx.x;

  // ---- per-half net weights (column j) ----
  const float* W0p = hi ? r2W0 : r1W0;
  const float* B0p = hi ? r2b0 : r1b0;
  const float* W1p = hi ? r2W1 : r1W1;
  const float* B1p = hi ? r2b1 : r1b1;
  const float* W2p = hi ? r2W2 : r1W2;
  const float* B2p = hi ? r2b2 : r1b2;
  float w0 = W0p[j], b0 = B0p[j], b1 = B1p[j], w2 = W2p[j], b2 = B2p[0];
  float sc = hi ? 0.2f : 0.3f;     // ystd scale for the net's output

  v2f W1v[16];                     // W1 column j, k-pairs
#pragma unroll
  for (int k = 0; k < 16; ++k)
    W1v[k] = mk2(W1p[(2 * k) * 32 + j], W1p[(2 * k + 1) * 32 + j]);

  // ---- r3 weights: W0C full (m-pairs), W1C k-half (k-pairs) ----
  v2f W0Cv[12];
#pragma unroll
  for (int m = 0; m < 12; ++m)
    W0Cv[m] = mk2(r3W0[(2 * m) * 32 + j], r3W0[(2 * m + 1) * 32 + j]);
  const int kbase = hi ? 16 : 0;
  v2f W1Cv[8];
#pragma unroll
  for (int k = 0; k < 8; ++k)
    W1Cv[k] = mk2(r3W1[(kbase + 2 * k) * 32 + j],
                  r3W1[(kbase + 2 * k + 1) * 32 + j]);
  float b0C = r3b0[j], b1C = r3b1[j], w2C = r3W2[j], b2C = r3b2[0];

  __shared__ __align__(16) float zs[24];      // z state
  __shared__ __align__(16) float zb[16];      // z4 prefix [xpseq[2:], x]
  __shared__ __align__(16) float h12[2][32];  // r1 / r2 hidden broadcast
  __shared__ __align__(16) float hR3[3][32];  // r3 hidden (z, z23, z4)

  float x0 = xz0[b * 26 + 0];
  float x1 = xz0[b * 26 + 1];
  if (!hi && j < 24) zs[j] = xz0[b * 26 + 2 + j];
  LDSBAR();

  // RK stage: low half runs r1(sx), high half runs r2(sy); both emit kx,ky.
  auto stage = [&](float sxv, float syv, float rc, float Caf,
                   float& kx, float& ky) {
    float s = hi ? syv : sxv;
    float h = tanh_fast(fmaf(s, w0, b0));
    LDSBAR();                      // prior readers of h12 done
    h12[hi][j] = h;
    LDSBAR();
    float a = dot32(&h12[hi][0], W1v, b1);
    float r = (rsum32(tanh_fast(a) * w2) + b2) * sc;
    float rp = __shfl_xor(r, 32);
    float ra = hi ? rp : r;        // r1 result
    float rb = hi ? r : rp;        // r2 result
    float Ca = fmaf(sxv, 0.3f, 0.5f);
    float Cb = fmaf(syv, 0.2f, 0.5f);
    float dCa = 0.1f * (Caf - Ca) - ra;
    float dCb = fmaf(-0.1f, Cb, ra - 3.0f * rb + rc);
    kx = dCa * (1.0f / 0.3f);
    ky = dCb * (1.0f / 0.2f);
  };

  float u = useq[b * TSTEPS];

  for (int t = 0; t < TSTEPS; ++t) {
    int tn = (t < TSTEPS - 1) ? (t + 1) : t;
    float u_nxt = useq[b * TSTEPS + tn];   // prefetch, consumed next iter
    float Caf = fmaf(u, 0.5f, 1.0f);

    if (lane == 0) out[b * TSTEPS + t] = make_float2(x0, x1);

    // z4 prefix into zb
    if (!hi && j < 16) {
      zb[j] = (j < 14) ? zs[j + 2] : ((j == 14) ? x0 : x1);
    }
    LDSBAR();

    // ---- r3 x3: low computes A1 (on z), high computes A4 (on z4) ----
    const float4* zp = (const float4*)(hi ? &zb[0] : &zs[0]);
    float4 z0 = zp[0], z1 = zp[1], z2 = zp[2], z3 = zp[3];
    const float4* up = (const float4*)&zs[16];     // shared upseq tail
    float4 u0 = up[0], u1 = up[1];
    v2f aa = mk2(b0C, 0.f), ab = mk2(0.f, 0.f);
    aa = pkfma(mk2(z0.x, z0.y), W0Cv[0], aa);
    ab = pkfma(mk2(z0.z, z0.w), W0Cv[1], ab);
    aa = pkfma(mk2(z1.x, z1.y), W0Cv[2], aa);
    ab = pkfma(mk2(z1.z, z1.w), W0Cv[3], ab);
    aa = pkfma(mk2(z2.x, z2.y), W0Cv[4], aa);
    ab = pkfma(mk2(z2.z, z2.w), W0Cv[5], ab);
    aa = pkfma(mk2(z3.x, z3.y), W0Cv[6], aa);
    ab = pkfma(mk2(z3.z, z3.w), W0Cv[7], ab);
    aa = pkfma(mk2(u0.x, u0.y), W0Cv[8], aa);
    ab = pkfma(mk2(u0.z, u0.w), W0Cv[9], ab);
    aa = pkfma(mk2(u1.x, u1.y), W0Cv[10], aa);
    ab = pkfma(mk2(u1.z, u1.w), W0Cv[11], ab);
    v2f as = aa + ab;
    float A = as.x + as.y;
    float Ap = __shfl_xor(A, 32);                  // partner's A
    float tA = tanh_fast(A);
    if (!hi) {
      hR3[0][j] = tA;                              // h(z)
      hR3[1][j] = tanh_fast(0.5f * (A + Ap));      // h(z23), exact linearity
    } else {
      hR3[2][j] = tA;                              // h(z4)
    }
    LDSBAR();
    float p0 = pdot16(&hR3[0][kbase], W1Cv);
    float p1 = pdot16(&hR3[1][kbase], W1Cv);
    float p2 = pdot16(&hR3[2][kbase], W1Cv);
    float o0 = p0 + __shfl_xor(p0, 32) + b1C;
    float o1 = p1 + __shfl_xor(p1, 32) + b1C;
    float o2 = p2 + __shfl_xor(p2, 32) + b1C;
    float rc1  = (rsum32(tanh_fast(o0) * w2C) + b2C) * 0.2f;
    float rc23 = (rsum32(tanh_fast(o1) * w2C) + b2C) * 0.2f;
    float rc4  = (rsum32(tanh_fast(o2) * w2C) + b2C) * 0.2f;

    // ---- RK stages ----
    float kx1, ky1, kx2, ky2, kx3, ky3, kx4, ky4;
    stage(x0, x1, rc1, Caf, kx1, ky1);
    stage(fmaf(kx1, 0.5f, x0), fmaf(ky1, 0.5f, x1), rc23, Caf, kx2, ky2);
    stage(fmaf(kx2, 0.5f, x0), fmaf(ky2, 0.5f, x1), rc23, Caf, kx3, ky3);
    stage(x0 + kx3, x1 + ky3, rc4, Caf, kx4, ky4);

    // ---- state update: zplus = [xpseq[2:], x, upseq[1:], u] ----
    float znew = 0.0f;
    bool updz = (!hi) && (j < 24);
    if (updz) znew = (j < 16) ? zb[j] : ((j < 23) ? zs[j + 1] : u);
    LDSBAR();                      // all reads of zs/zb complete
    if (updz) zs[j] = znew;
    x0 += (kx1 + 2.0f * (kx2 + kx3) + kx4) * (1.0f / 6.0f);
    x1 += (ky1 + 2.0f * (ky2 + ky3) + ky4) * (1.0f / 6.0f);
    u = u_nxt;
    LDSBAR();                      // zs visible to next iteration's readers
  }
}

extern "C" void kernel_launch(void* const* d_in, const int* in_sizes, int n_in,
                              void* d_out, int out_size, void* d_ws, size_t ws_size,
                              hipStream_t stream) {
  const float* p[20];
  for (int i = 0; i < 20; ++i) p[i] = (const float*)d_in[i];
  reac_kernel<<<dim3(4096), dim3(64), 0, stream>>>(
      p[0], p[1], p[2], p[3], p[4], p[5], p[6], p[7], p[8], p[9], p[10],
      p[11], p[12], p[13], p[14], p[15], p[16], p[17], p[18], p[19],
      (float2*)d_out);
}

// Round 10
// 871.558 us; speedup vs baseline: 1.0862x; 1.0862x over previous
//
#include <hip/hip_runtime.h>

#define DEVINL static __device__ __forceinline__
// A wave's LDS ops are serviced in issue order (in-order lgkm for DS), so
// same-wave WAR/RAW through LDS needs only a compiler reorder fence, not a
// hardware s_waitcnt drain.
#define CFENCE() asm volatile("" ::: "memory")

typedef float v2f __attribute__((ext_vector_type(2)));

DEVINL v2f mk2(float a, float b) { v2f r; r.x = a; r.y = b; return r; }
// One V_PK_FMA_F32: two IEEE fp32 FMAs per lane per issue.
DEVINL v2f pkfma(v2f a, v2f b, v2f c) { return __builtin_elementwise_fma(a, b, c); }

constexpr float KE = 2.885390081777927f;   // 2*log2(e)

#if __has_builtin(__builtin_amdgcn_exp2f)
DEVINL float exp2_fast(float x) { return __builtin_amdgcn_exp2f(x); }
#else
DEVINL float exp2_fast(float x) { return __expf(x * 0.6931471805599453f); }
#endif

// tanh(x) given t = x*2*log2(e) (the KE factor is folded into weights/biases):
// tanh = 1 - 2/(2^t + 1); never NaN.
DEVINL float tanh_pre(float t) {
  float e = exp2_fast(t);
  return 1.0f - 2.0f * __builtin_amdgcn_rcpf(e + 1.0f);
}

template <int CTRL>
DEVINL float dpp_add(float v) {
  int t = __builtin_amdgcn_update_dpp(0, __float_as_int(v), CTRL, 0xF, 0xF, true);
  return v + __int_as_float(t);
}
// Sum across each 32-lane half-wave; result replicated within the half.
DEVINL float rsum32(float v) {
  v = dpp_add<0xB1>(v);    // quad_perm [1,0,3,2]
  v = dpp_add<0x4E>(v);    // quad_perm [2,3,0,1]
  v = dpp_add<0x141>(v);   // row_half_mirror
  v = dpp_add<0x140>(v);   // row_mirror
  v += __int_as_float(__builtin_amdgcn_ds_swizzle(__float_as_int(v), 0x401F)); // xor16
  return v;
}

// 32-wide dot vs an LDS row (uniform address per half), packed fp32.
DEVINL float dot32(const float* hrow, const v2f* W, float bias) {
  const float4* hp = (const float4*)hrow;
  v2f a0 = mk2(bias, 0.f), a1 = mk2(0.f, 0.f);
  v2f a2 = mk2(0.f, 0.f), a3 = mk2(0.f, 0.f);
#pragma unroll
  for (int q = 0; q < 8; q += 2) {
    float4 x = hp[q], y = hp[q + 1];
    a0 = pkfma(mk2(x.x, x.y), W[2 * q + 0], a0);
    a1 = pkfma(mk2(x.z, x.w), W[2 * q + 1], a1);
    a2 = pkfma(mk2(y.x, y.y), W[2 * q + 2], a2);
    a3 = pkfma(mk2(y.z, y.w), W[2 * q + 3], a3);
  }
  v2f s = (a0 + a1) + (a2 + a3);
  return s.x + s.y;
}
// 16-wide partial dot (k-split r3 layer 1), packed fp32.
DEVINL float pdot16(const float* hrow, const v2f* W) {
  const float4* hp = (const float4*)hrow;
  v2f a0 = mk2(0.f, 0.f), a1 = mk2(0.f, 0.f);
  float4 x = hp[0], y = hp[1];
  a0 = pkfma(mk2(x.x, x.y), W[0], a0);
  a1 = pkfma(mk2(x.z, x.w), W[1], a1);
  a0 = pkfma(mk2(y.x, y.y), W[2], a0);
  a1 = pkfma(mk2(y.z, y.w), W[3], a1);
  x = hp[2]; y = hp[3];
  a0 = pkfma(mk2(x.x, x.y), W[4], a0);
  a1 = pkfma(mk2(x.z, x.w), W[5], a1);
  a0 = pkfma(mk2(y.x, y.y), W[6], a0);
  a1 = pkfma(mk2(y.z, y.w), W[7], a1);
  v2f s = a0 + a1;
  return s.x + s.y;
}

constexpr int TSTEPS = 256;

// wave = 1 batch element; lanes 0-31 = net r1 duties, lanes 32-63 = net r2.
// grid 4096 x 1 wave = 16 waves/CU = 4 waves/EU (exact), hence (4,4).
__global__ __attribute__((amdgpu_flat_work_group_size(64, 64)))
__attribute__((amdgpu_waves_per_eu(4, 4))) void reac_kernel(
    const float* __restrict__ useq,   // [B][T] f32
    const float* __restrict__ xz0,    // [B][26] f32
    const float* __restrict__ r1W0, const float* __restrict__ r1b0,
    const float* __restrict__ r1W1, const float* __restrict__ r1b1,
    const float* __restrict__ r1W2, const float* __restrict__ r1b2,
    const float* __restrict__ r2W0, const float* __restrict__ r2b0,
    const float* __restrict__ r2W1, const float* __restrict__ r2b1,
    const float* __restrict__ r2W2, const float* __restrict__ r2b2,
    const float* __restrict__ r3W0, const float* __restrict__ r3b0,
    const float* __restrict__ r3W1, const float* __restrict__ r3b1,
    const float* __restrict__ r3W2, const float* __restrict__ r3b2,
    float2* __restrict__ out)         // [B][T] -> (x0,x1) f32
{
  const int lane = threadIdx.x;
  const int j = lane & 31;
  const bool hi = lane >= 32;      // high half = r2 net
  const int b = blockIdx.x;
  const int xaddr = ((lane ^ 32) << 2);   // ds_bpermute partner address

  auto xchg = [&](float v) -> float {
    return __int_as_float(__builtin_amdgcn_ds_bpermute(xaddr, __float_as_int(v)));
  };

  // ---- per-half net weights (column j), tanh-prescale KE folded in ----
  const float* W0p = hi ? r2W0 : r1W0;
  const float* B0p = hi ? r2b0 : r1b0;
  const float* W1p = hi ? r2W1 : r1W1;
  const float* B1p = hi ? r2b1 : r1b1;
  const float* W2p = hi ? r2W2 : r1W2;
  const float* B2p = hi ? r2b2 : r1b2;
  const float sc = hi ? 0.2f : 0.3f;          // ystd scale of the net output
  float w0K = W0p[j] * KE, b0K = B0p[j] * KE;
  float b1K = B1p[j] * KE;
  float w2sc = W2p[j] * sc, b2sc = B2p[0] * sc;

  v2f W1v[16];                     // W1 column j, k-pairs, *KE
#pragma unroll
  for (int k = 0; k < 16; ++k)
    W1v[k] = mk2(W1p[(2 * k) * 32 + j] * KE, W1p[(2 * k + 1) * 32 + j] * KE);

  // ---- r3 weights: W0C full (m-pairs, *KE), W1C k-half (k-pairs, *KE) ----
  v2f W0Cv[12];
#pragma unroll
  for (int m = 0; m < 12; ++m)
    W0Cv[m] = mk2(r3W0[(2 * m) * 32 + j] * KE, r3W0[(2 * m + 1) * 32 + j] * KE);
  const int kbase = hi ? 16 : 0;
  v2f W1Cv[8];
#pragma unroll
  for (int k = 0; k < 8; ++k)
    W1Cv[k] = mk2(r3W1[(kbase + 2 * k) * 32 + j] * KE,
                  r3W1[(kbase + 2 * k + 1) * 32 + j] * KE);
  float b0CK = r3b0[j] * KE, b1CK = r3b1[j] * KE;
  float w2C02 = r3W2[j] * 0.2f;
  float b2Cs = r3b2[0] * 0.2f - 0.05f;   // folds the -F/V*0.5 term of dCb

  __shared__ __align__(16) float zs[24];      // z state
  __shared__ __align__(16) float zb[16];      // z4 prefix [xpseq[2:], x]
  __shared__ __align__(16) float h12[2][32];  // r1 / r2 hidden broadcast
  __shared__ __align__(16) float hR3[3][32];  // r3 hidden (z, z23, z4)

  float x0 = xz0[b * 26 + 0];
  float x1 = xz0[b * 26 + 1];
  if (!hi && j < 24) zs[j] = xz0[b * 26 + 2 + j];
  CFENCE();

  // RK stage: low half runs r1(sx), high half runs r2(sy); both emit kx,ky.
  // rcp_ = rc - 0.05 (pre-folded); CafF = 0.05*u + 0.05.
  auto stage = [&](float sxv, float syv, float rcp_, float CafF,
                   float& kx, float& ky) {
    float s = hi ? syv : sxv;
    float h = tanh_pre(fmaf(s, w0K, b0K));
    CFENCE();                      // order write after previous readers
    h12[hi][j] = h;
    CFENCE();                      // order reads after the write
    float a = dot32(&h12[hi][0], W1v, b1K);
    float r = rsum32(tanh_pre(a) * w2sc) + b2sc;
    float rp = xchg(r);
    float ra = hi ? rp : r;        // r1 result
    float rb = hi ? r : rp;        // r2 result
    // dCa = 0.05u+0.05 - 0.03*sx - ra ; dCb = -0.02*sy + ra - 3rb + rc - 0.05
    float dCa = fmaf(-0.03f, sxv, CafF) - ra;
    float dCb = fmaf(-0.02f, syv, fmaf(-3.0f, rb, ra) + rcp_);
    kx = dCa * (1.0f / 0.3f);
    ky = dCb * (1.0f / 0.2f);
  };

  float u = useq[b * TSTEPS];

  for (int t = 0; t < TSTEPS; ++t) {
    int tn = (t < TSTEPS - 1) ? (t + 1) : t;
    float u_nxt = useq[b * TSTEPS + tn];   // prefetch, consumed next iter
    float CafF = fmaf(u, 0.05f, 0.05f);

    if (lane == 0) out[b * TSTEPS + t] = make_float2(x0, x1);

    // z4 prefix into zb
    CFENCE();
    if (!hi && j < 16) {
      zb[j] = (j < 14) ? zs[j + 2] : ((j == 14) ? x0 : x1);
    }
    CFENCE();

    // ---- r3 x3: low computes A1(z), high computes A4(z4); all pre-scaled ----
    const float4* zp = (const float4*)(hi ? &zb[0] : &zs[0]);
    float4 z0 = zp[0], z1 = zp[1], z2 = zp[2], z3 = zp[3];
    const float4* up = (const float4*)&zs[16];     // shared upseq tail
    float4 u0 = up[0], u1 = up[1];
    v2f aa = mk2(b0CK, 0.f), ab = mk2(0.f, 0.f);
    aa = pkfma(mk2(z0.x, z0.y), W0Cv[0], aa);
    ab = pkfma(mk2(z0.z, z0.w), W0Cv[1], ab);
    aa = pkfma(mk2(z1.x, z1.y), W0Cv[2], aa);
    ab = pkfma(mk2(z1.z, z1.w), W0Cv[3], ab);
    aa = pkfma(mk2(z2.x, z2.y), W0Cv[4], aa);
    ab = pkfma(mk2(z2.z, z2.w), W0Cv[5], ab);
    aa = pkfma(mk2(z3.x, z3.y), W0Cv[6], aa);
    ab = pkfma(mk2(z3.z, z3.w), W0Cv[7], ab);
    aa = pkfma(mk2(u0.x, u0.y), W0Cv[8], aa);
    ab = pkfma(mk2(u0.z, u0.w), W0Cv[9], ab);
    aa = pkfma(mk2(u1.x, u1.y), W0Cv[10], aa);
    ab = pkfma(mk2(u1.z, u1.w), W0Cv[11], ab);
    v2f as = aa + ab;
    float A = as.x + as.y;          // pre-scaled activation
    float Ap = xchg(A);             // partner's A
    float tA = tanh_pre(A);
    if (!hi) {
      hR3[0][j] = tA;                              // h(z)
      hR3[1][j] = tanh_pre(0.5f * (A + Ap));       // h(z23), exact linearity
    } else {
      hR3[2][j] = tA;                              // h(z4)
    }
    CFENCE();
    float p0 = pdot16(&hR3[0][kbase], W1Cv);
    float p1 = pdot16(&hR3[1][kbase], W1Cv);
    float p2 = pdot16(&hR3[2][kbase], W1Cv);
    float o0 = p0 + xchg(p0) + b1CK;
    float o1 = p1 + xchg(p1) + b1CK;
    float o2 = p2 + xchg(p2) + b1CK;
    float rc1  = rsum32(tanh_pre(o0) * w2C02) + b2Cs;   // = rc - 0.05
    float rc23 = rsum32(tanh_pre(o1) * w2C02) + b2Cs;
    float rc4  = rsum32(tanh_pre(o2) * w2C02) + b2Cs;

    // ---- RK stages ----
    float kx1, ky1, kx2, ky2, kx3, ky3, kx4, ky4;
    stage(x0, x1, rc1, CafF, kx1, ky1);
    stage(fmaf(kx1, 0.5f, x0), fmaf(ky1, 0.5f, x1), rc23, CafF, kx2, ky2);
    stage(fmaf(kx2, 0.5f, x0), fmaf(ky2, 0.5f, x1), rc23, CafF, kx3, ky3);
    stage(x0 + kx3, x1 + ky3, rc4, CafF, kx4, ky4);

    // ---- state update: zplus = [xpseq[2:], x, upseq[1:], u] ----
    float znew = 0.0f;
    bool updz = (!hi) && (j < 24);
    if (updz) znew = (j < 16) ? zb[j] : ((j < 23) ? zs[j + 1] : u);
    CFENCE();                      // reads ordered before the overwrite
    if (updz) zs[j] = znew;
    x0 += (kx1 + 2.0f * (kx2 + kx3) + kx4) * (1.0f / 6.0f);
    x1 += (ky1 + 2.0f * (ky2 + ky3) + ky4) * (1.0f / 6.0f);
    u = u_nxt;
    CFENCE();                      // zs write ordered before next-iter reads
  }
}

extern "C" void kernel_launch(void* const* d_in, const int* in_sizes, int n_in,
                              void* d_out, int out_size, void* d_ws, size_t ws_size,
                              hipStream_t stream) {
  const float* p[20];
  for (int i = 0; i < 20; ++i) p[i] = (const float*)d_in[i];
  reac_kernel<<<dim3(4096), dim3(64), 0, stream>>>(
      p[0], p[1], p[2], p[3], p[4], p[5], p[6], p[7], p[8], p[9], p[10],
      p[11], p[12], p[13], p[14], p[15], p[16], p[17], p[18], p[19],
      (float2*)d_out);
}